// Round 11
// baseline (236.170 us; speedup 1.0000x reference)
//
#include <hip/hip_runtime.h>
#include <hip/hip_bf16.h>

// CausalAttention: B=4, S=2048, d=1024, single head, causal. fp32 I/O, bf16 MFMA inside.
//
// R19: visibility round (deliberate, bounded, revertible). Accounting says scores+PV
//      hold ~110-130 us but NEITHER has ever produced a counter row (QKV's 66-68 us
//      instances always fill top-5; R14 proved scores < 46). Split QKV into three
//      per-matrix dispatches (~23-27 us each) so scores (MODE 1) and PV (MODE 2)
//      MUST surface with full counters. Known cost ~+12-15 us (measured R13->R14,
//      same split). R20 re-fuses QKV and fixes what the counters indict.
//      All R16/R18 wins kept: V written transposed in the projection epilogue
//      (via cOff: global column offset selects output matrix), rowsum via ones-MFMA
//      in PV, 544-tile tri grid, panel-pinned PV map, merged prep.
//
// Pipeline (6 dispatches this round only):
//   1) prep: Wt[3072][1024] = {Wq,Wk,Wv}^T bf16  ||  Xb = bf16(x)
//   2) Q  = Xb * Wq^T            (MODE 3, cOff=0,    grid 8x64)
//   3) K  = Xb * Wk^T            (MODE 3, cOff=1024, grid 8x64)
//   4) Vt = (Xb * Wv^T)^T        (MODE 3, cOff=2048, grid 8x64; transposed epilogue)
//   5) E = masked-exp(Q*K^T/32)  (MODE 1, 128^2, flat tri grid 544; no rowsum)
//   6) out = (E*V) / (E*ones)    (MODE 2, 128^2, panel-pinned 512; rowsum via MFMA)

typedef __bf16 bf16_t;
typedef __bf16 bf16x8 __attribute__((ext_vector_type(8)));
typedef float f32x4 __attribute__((ext_vector_type(4)));

__device__ __forceinline__ void load_lds16(const bf16_t* g, bf16_t* l) {
  __builtin_amdgcn_global_load_lds(
      (__attribute__((address_space(1))) void*)(void*)g,
      (__attribute__((address_space(3))) void*)l,
      16, 0, 0);
}

// C[m][n] = sum_k A[m][k]*B[n][k]  (A:[M][K], B:[N][K] row-major bf16)
// MODE: 1 scores: flat triangular grid, epilogue mask+exp (no rowsum)
//       2 pv: panel-pinned flat grid, K clamped, rowsum via ones-MFMA, epilogue 1/rs
//       3 projection; global col = colBase + cOff selects {Q, K, Vt-transposed} output
// LDS swizzle: 16B chunk position p of row r holds global chunk p ^ (r&7);
// fragment reads hit all 32 banks 2-way (free, m136). Conflicts measured 0 (R5-R18).
template <int BMv, int BNv, int NW, int MODE, typename OT>
__global__ __launch_bounds__(NW * 64)
void gemm_nt_bf16(const bf16_t* __restrict__ A, const bf16_t* __restrict__ B,
                  OT* __restrict__ C0, OT* __restrict__ C1, OT* __restrict__ C2,
                  int M, int K, int ldc, int cOff,
                  long strideA, long strideB, long strideC)
{
  constexpr int MW = BMv / 64;       // wave grid: MW x (NW/MW)
  constexpr int RA = BMv / NW;       // rows staged per wave (A)
  constexpr int RB = BNv / NW;       // rows staged per wave (B)

  int bx, by, bz;
  if constexpr (MODE == 1) {
    // Flat XCD-balanced lower-triangle enumeration (S=2048, 128-tiles, 16 panels/batch).
    // XCD x (= blockIdx.x & 7, m09 round-robin) owns panels {x, 15-x} of every batch:
    // weight (x+1) + (16-x) = 17 tiles per batch -> 68 per XCD, exact balance.
    const int f = blockIdx.x;          // 544 blocks
    const int x = f & 7;
    const int j = f >> 3;              // [0, 68)
    bz = j / 17;
    const int r = j % 17;
    by = (r <= x) ? x : 15 - x;
    bx = (r <= x) ? r : r - (x + 1);
  } else if constexpr (MODE == 2) {
    // PV panel-pinned flat grid: 512 blocks. XCD = f&7 owns 8 E row-panels
    // (4 heavy-first pairs; (16-pr)+(pr+1)=17 -> 68 K-units per XCD exactly).
    // bx fastest: the 8 col-blocks of a panel are consecutive ON ONE XCD -> A-panel
    // fetched once, ~2.2 MB/XCD in L2 (R14: 78 MB FETCH with the un-pinned map).
    const int f  = blockIdx.x;
    const int xcd = f & 7;
    const int i  = f >> 3;             // [0,64) within XCD
    bx = i & 7;
    const int p  = i >> 3;             // [0,8) panel slot
    const int j  = p & 3;              // pair index
    const int heavy = (p < 4);         // heavy panels first
    const int g  = xcd * 4 + j;        // [0,32) global (bz,pr) pair
    bz = g >> 3;
    const int pr = g & 7;
    by = heavy ? (15 - pr) : pr;
  } else {
    // XCD-aware remap: pin all x-blocks of an A-panel (y,z) to one XCD.
    // Requires (gridDim.y*gridDim.z) % 8 == 0 -- true here (64).
    const int gx = gridDim.x, gy = gridDim.y;
    const int NP = gy * gridDim.z;
    const int P  = NP >> 3;                         // panels per XCD
    const int flat = blockIdx.x + gx * (blockIdx.y + gy * blockIdx.z);
    const int xcd  = flat & 7;
    const int i    = flat >> 3;
    const int pan  = xcd * P + (i % P);
    bx = i / P;
    by = pan % gy;
    bz = pan / gy;
  }

  const int rowBase = by * BMv;
  const int colBase = bx * BNv;

  __shared__ __align__(16) bf16_t sA[BMv * 64];
  __shared__ __align__(16) bf16_t sB[BNv * 64];

  A += (size_t)bz * strideA;
  B += (size_t)bz * strideB;

  const int tid  = threadIdx.x;
  const int wave = tid >> 6;
  const int lane = tid & 63;
  const int quad = lane >> 4;
  const int ln16 = lane & 15;

  const int wm = (wave % MW) * 64;
  const int wn = (wave / MW) * 64;

  const int rA = lane >> 3;                       // 0..7 row-in-group
  const int sColOff = ((lane & 7) ^ rA) * 8;      // swizzled chunk offset (elems)
  const bf16_t* pA = A + (size_t)(rowBase + wave * RA + rA) * K + sColOff;
  const bf16_t* pB = B + (size_t)(colBase + wave * RB + rA) * K + sColOff;
  bf16_t* ldsA = sA + wave * RA * 64;
  bf16_t* ldsB = sB + wave * RB * 64;

  f32x4 acc[4][4] = {};
  f32x4 acc_rs[4] = {};                           // MODE 2: per-row E sums (ones-MFMA)
  bf16x8 ones;
#pragma unroll
  for (int i = 0; i < 8; i++) ones[i] = (bf16_t)1.0f;

  const int Kend = (MODE == 2) ? (K < rowBase + BMv ? K : rowBase + BMv) : K;

  for (int k0 = 0; k0 < Kend; k0 += 64) {
#pragma unroll
    for (int j = 0; j < RA / 8; j++)
      load_lds16(pA + k0 + (size_t)(8 * j) * K, ldsA + j * 512);
#pragma unroll
    for (int j = 0; j < RB / 8; j++)
      load_lds16(pB + k0 + (size_t)(8 * j) * K, ldsB + j * 512);
    __syncthreads();   // drains vmcnt for all waves

#pragma unroll
    for (int kk = 0; kk < 2; kk++) {
      bf16x8 af[4], bfr[4];
#pragma unroll
      for (int mt = 0; mt < 4; mt++) {
        const int row = wm + mt * 16 + ln16;
        af[mt] = *(const bf16x8*)(sA + row * 64 + (((kk * 4 + quad) ^ (row & 7)) * 8));
      }
#pragma unroll
      for (int nt = 0; nt < 4; nt++) {
        const int row = wn + nt * 16 + ln16;
        bfr[nt] = *(const bf16x8*)(sB + row * 64 + (((kk * 4 + quad) ^ (row & 7)) * 8));
      }
#pragma unroll
      for (int mt = 0; mt < 4; mt++) {
#pragma unroll
        for (int nt = 0; nt < 4; nt++)
          acc[mt][nt] = __builtin_amdgcn_mfma_f32_16x16x32_bf16(af[mt], bfr[nt], acc[mt][nt], 0, 0, 0);
        if constexpr (MODE == 2)
          acc_rs[mt] = __builtin_amdgcn_mfma_f32_16x16x32_bf16(af[mt], ones, acc_rs[mt], 0, 0, 0);
      }
    }
    __syncthreads();
  }

  // epilogue: C/D layout col = lane&15, row = quad*4 + r  [measured m89/m91]
  if constexpr (MODE == 3) {
    const int gcol = colBase + cOff;
    const int which = gcol >> 10;                  // 0=Q, 1=K, 2=Vt
    const int cb = gcol & 1023;
    if (which == 2) {
      // V-third: write transposed into Vt[b][e][s]  (b=row>>11, e=col, s=row&2047).
      // Each block covers 128 contiguous s per e-row -> 64B lines fully written
      // within one block/XCD -> L2 write-merge keeps HBM traffic at 33.5 MB.
#pragma unroll
      for (int mt = 0; mt < 4; mt++) {
#pragma unroll
        for (int r = 0; r < 4; r++) {
          const int row = rowBase + wm + mt * 16 + quad * 4 + r;
          const size_t vb = (size_t)(row >> 11) * (1024 * 2048) + (row & 2047);
#pragma unroll
          for (int nt = 0; nt < 4; nt++) {
            const int col = cb + wn + nt * 16 + ln16;
            C2[vb + (size_t)col * 2048] = (OT)acc[mt][nt][r];
          }
        }
      }
    } else {
      OT* Cw = which ? C1 : C0;
#pragma unroll
      for (int mt = 0; mt < 4; mt++) {
#pragma unroll
        for (int r = 0; r < 4; r++) {
          const int row = rowBase + wm + mt * 16 + quad * 4 + r;
#pragma unroll
          for (int nt = 0; nt < 4; nt++) {
            const int col = cb + wn + nt * 16 + ln16;
            Cw[(size_t)row * ldc + col] = (OT)acc[mt][nt][r];
          }
        }
      }
    }
    return;
  }

  OT* Cw = C0 + (size_t)bz * strideC;
#pragma unroll
  for (int mt = 0; mt < 4; mt++) {
#pragma unroll
    for (int r = 0; r < 4; r++) {
      const int row = rowBase + wm + mt * 16 + quad * 4 + r;
      const float rinv = (MODE == 2) ? 1.0f / acc_rs[mt][r] : 1.0f;
#pragma unroll
      for (int nt = 0; nt < 4; nt++) {
        const int col = colBase + wn + nt * 16 + ln16;
        float v = acc[mt][nt][r];
        if constexpr (MODE == 1) {
          v = (col <= row) ? __expf(v * 0.03125f) : 0.0f;   // s/sqrt(1024)
        } else {
          v *= rinv;
        }
        Cw[(size_t)row * ldc + col] = (OT)v;
      }
    }
  }
}

// Fused prep: blocks [0,3072) transpose {Wq,Wk,Wv} fp32 -> bf16 into Wt [3D][D];
// blocks [3072, 7168) convert x fp32 -> bf16 (8 elems/thread, vectorized).
__global__ __launch_bounds__(256)
void prep(const float* __restrict__ w0, const float* __restrict__ w1,
          const float* __restrict__ w2, bf16_t* __restrict__ wt, int D,
          const float* __restrict__ x, bf16_t* __restrict__ xb, long n)
{
  const int b = blockIdx.x;
  const int tid = threadIdx.x;
  __shared__ float tile[32][33];
  if (b < 3072) {
    const int z  = b >> 10;                        // 0..2 selects W matrix
    const int xy = b & 1023;
    const int c0 = (xy & 31) * 32, r0 = (xy >> 5) * 32;
    const int tx = tid & 31, ty = tid >> 5;        // (32, 8)
    const float* in = (z == 0) ? w0 : (z == 1) ? w1 : w2;
    bf16_t* o = wt + (size_t)z * D * D;
#pragma unroll
    for (int i = 0; i < 32; i += 8)
      tile[ty + i][tx] = in[(size_t)(r0 + ty + i) * D + (c0 + tx)];
    __syncthreads();
#pragma unroll
    for (int i = 0; i < 32; i += 8)
      o[(size_t)(c0 + ty + i) * D + (r0 + tx)] = (bf16_t)tile[tx][ty + i];
  } else {
    const long i = ((long)(b - 3072) * 256 + tid) * 8;
    if (i + 7 < n) {
      float4 a = *(const float4*)(x + i);
      float4 c = *(const float4*)(x + i + 4);
      bf16x8 o;
      o[0] = (bf16_t)a.x; o[1] = (bf16_t)a.y; o[2] = (bf16_t)a.z; o[3] = (bf16_t)a.w;
      o[4] = (bf16_t)c.x; o[5] = (bf16_t)c.y; o[6] = (bf16_t)c.z; o[7] = (bf16_t)c.w;
      *(bf16x8*)(xb + i) = o;
    }
  }
}

extern "C" void kernel_launch(void* const* d_in, const int* in_sizes, int n_in,
                              void* d_out, int out_size, void* d_ws, size_t ws_size,
                              hipStream_t stream) {
  const float* x  = (const float*)d_in[0];
  const float* Wq = (const float*)d_in[1];
  const float* Wk = (const float*)d_in[2];
  const float* Wv = (const float*)d_in[3];
  float* out = (float*)d_out;

  const int Bb = 4, S = 2048, D = 1024;
  const int M = Bb * S;  // 8192

  // ws (bf16 elems): Q | K | Vt | Wt(3*D*D) | Xb | (tail)   = 90,177,536 B (fits)
  // Sc (Bb*S*S == 2*M*D) aliases [Xb | tail].
  bf16_t* ws = (bf16_t*)d_ws;
  bf16_t* Q   = ws;
  bf16_t* Kp  = Q  + (size_t)M * D;
  bf16_t* Vt  = Kp + (size_t)M * D;
  bf16_t* Wt  = Vt + (size_t)M * D;          // [3072][1024] stacked
  bf16_t* Xb  = Wt + 3 * (size_t)D * D;
  bf16_t* Sc  = Xb;

  // 1) prep: W transpose+cvt (3072 blocks) || x cvt (4096 blocks)
  prep<<<dim3(3072 + 4096), dim3(256), 0, stream>>>(Wq, Wk, Wv, Wt, D, x, Xb, (long)M * D);

  // 2-4) projections, one dispatch per matrix (grid 8x64 = 512 blocks each).
  //      VISIBILITY ROUND: each ~23-27 us so scores/PV must surface in top-5.
  gemm_nt_bf16<128, 128, 4, 3, bf16_t><<<dim3(D / 128, M / 128, 1), dim3(256), 0, stream>>>(
      Xb, Wt,                     Q, Kp, Vt, M, D, D, 0,    0, 0, 0);
  gemm_nt_bf16<128, 128, 4, 3, bf16_t><<<dim3(D / 128, M / 128, 1), dim3(256), 0, stream>>>(
      Xb, Wt + (size_t)D * D,     Q, Kp, Vt, M, D, D, 1024, 0, 0, 0);
  gemm_nt_bf16<128, 128, 4, 3, bf16_t><<<dim3(D / 128, M / 128, 1), dim3(256), 0, stream>>>(
      Xb, Wt + 2 * (size_t)D * D, Q, Kp, Vt, M, D, D, 2048, 0, 0, 0);

  // 5) E = masked-exp(Q*K^T/32)  (flat triangular grid: 544 tiles, 68/XCD exact)
  gemm_nt_bf16<128, 128, 4, 1, bf16_t><<<dim3(544, 1, 1), dim3(256), 0, stream>>>(
      Q, Kp, Sc, Sc, Sc, S, D, S, 0, (long)S * D, (long)S * D, (long)S * S);

  // 6) out = (E*V) / (E*ones)  (panel-pinned flat grid: 512 blocks, 68 K-units/XCD)
  gemm_nt_bf16<128, 128, 4, 2, float><<<dim3(512, 1, 1), dim3(256), 0, stream>>>(
      Sc, Vt, out, out, out, S, S, D, 0, (long)S * S, (long)D * S, (long)S * D);
}

// Round 12
// 217.778 us; speedup vs baseline: 1.0845x; 1.0845x over previous
//
#include <hip/hip_runtime.h>
#include <hip/hip_bf16.h>

// CausalAttention: B=4, S=2048, d=1024, single head, causal. fp32 I/O, bf16 MFMA inside.
//
// R20: occupancy fix for scores/PV, QKV re-fused.
//      R19 counters (PV finally visible): 45.5 us, FETCH 23 MB (panel-pinning VERIFIED:
//      78->23 MB), MfmaUtil 16%, VALUBusy 23%, Occupancy 10%. PV is TLP-starved, not
//      memory-bound: 4-wave blocks at 2/CU decay to 1 lone block (1 wave/SIMD) during
//      the heavy-K tail -> 2-barrier drain fully exposed. Scores has the same flavor
//      (544 tiles = 2.125 blocks/CU quantization).
//      Fix: NW=8 waves on the same 128^2 tile for MODE 1/2 (wave grid 2x4, per-wave
//      64x32, acc[4][2]). Same MFMA count, same LDS, but a lone block = 2 waves/SIMD
//      (m114 overlap), 2-3 blocks = 4-6/SIMD. Maps/swizzle/K-loop/epilogue untouched.
//      QKV back to the proven fused 4-wave dispatch (66-68 us across R12-R18).
//
// Pipeline (4 dispatches):
//   1) prep: Wt[3072][1024] = {Wq,Wk,Wv}^T bf16  ||  Xb = bf16(x)
//   2) {Q,K,Vt} = Xb * Wt^T      (MODE 3, 4-wave 128^2, grid 24x64; V transposed)
//   3) E = masked-exp(Q*K^T/32)  (MODE 1, 8-wave 128^2, flat tri grid 544)
//   4) out = (E*V) / (E*ones)    (MODE 2, 8-wave 128^2, panel-pinned 512)

typedef __bf16 bf16_t;
typedef __bf16 bf16x8 __attribute__((ext_vector_type(8)));
typedef float f32x4 __attribute__((ext_vector_type(4)));

__device__ __forceinline__ void load_lds16(const bf16_t* g, bf16_t* l) {
  __builtin_amdgcn_global_load_lds(
      (__attribute__((address_space(1))) void*)(void*)g,
      (__attribute__((address_space(3))) void*)l,
      16, 0, 0);
}

// C[m][n] = sum_k A[m][k]*B[n][k]  (A:[M][K], B:[N][K] row-major bf16)
// MODE: 1 scores: flat triangular grid, epilogue mask+exp (no rowsum)
//       2 pv: panel-pinned flat grid, K clamped, rowsum via ones-MFMA, epilogue 1/rs
//       3 fused qkv split; V-third written transposed into Vt
// Wave grid: MW x (NW/MW); per-wave tile 64 x WN where WN = BNv*MW/NW.
// LDS swizzle: 16B chunk position p of row r holds global chunk p ^ (r&7);
// fragment reads hit all 32 banks 2-way (free, m136). Conflicts measured 0 (R5-R19).
template <int BMv, int BNv, int NW, int MODE, typename OT>
__global__ __launch_bounds__(NW * 64)
void gemm_nt_bf16(const bf16_t* __restrict__ A, const bf16_t* __restrict__ B,
                  OT* __restrict__ C0, OT* __restrict__ C1, OT* __restrict__ C2,
                  int M, int K, int ldc,
                  long strideA, long strideB, long strideC)
{
  constexpr int MW = BMv / 64;       // wave rows
  constexpr int WN = BNv * MW / NW;  // per-wave N span (64 @ NW=4, 32 @ NW=8)
  constexpr int NT = WN / 16;        // B fragments per wave (4 or 2)
  constexpr int RA = BMv / NW;       // rows staged per wave (A)
  constexpr int RB = BNv / NW;       // rows staged per wave (B)

  int bx, by, bz;
  if constexpr (MODE == 1) {
    // Flat XCD-balanced lower-triangle enumeration (S=2048, 128-tiles, 16 panels/batch).
    // XCD x (= blockIdx.x & 7, m09 round-robin) owns panels {x, 15-x} of every batch:
    // weight (x+1) + (16-x) = 17 tiles per batch -> 68 per XCD, exact balance.
    const int f = blockIdx.x;          // 544 blocks
    const int x = f & 7;
    const int j = f >> 3;              // [0, 68)
    bz = j / 17;
    const int r = j % 17;
    by = (r <= x) ? x : 15 - x;
    bx = (r <= x) ? r : r - (x + 1);
  } else if constexpr (MODE == 2) {
    // PV panel-pinned flat grid: 512 blocks. XCD = f&7 owns 8 E row-panels
    // (4 heavy-first pairs; (16-pr)+(pr+1)=17 -> 68 K-units per XCD exactly).
    // bx fastest: the 8 col-blocks of a panel are consecutive ON ONE XCD -> A-panel
    // fetched once (VERIFIED R19: FETCH 78 -> 23 MB).
    const int f  = blockIdx.x;
    const int xcd = f & 7;
    const int i  = f >> 3;             // [0,64) within XCD
    bx = i & 7;
    const int p  = i >> 3;             // [0,8) panel slot
    const int j  = p & 3;              // pair index
    const int heavy = (p < 4);         // heavy panels first
    const int g  = xcd * 4 + j;        // [0,32) global (bz,pr) pair
    bz = g >> 3;
    const int pr = g & 7;
    by = heavy ? (15 - pr) : pr;
  } else {
    // XCD-aware remap: pin all x-blocks of an A-panel (y,z) to one XCD.
    // Requires (gridDim.y*gridDim.z) % 8 == 0 -- true here (64).
    const int gx = gridDim.x, gy = gridDim.y;
    const int NP = gy * gridDim.z;
    const int P  = NP >> 3;                         // panels per XCD
    const int flat = blockIdx.x + gx * (blockIdx.y + gy * blockIdx.z);
    const int xcd  = flat & 7;
    const int i    = flat >> 3;
    const int pan  = xcd * P + (i % P);
    bx = i / P;
    by = pan % gy;
    bz = pan / gy;
  }

  const int rowBase = by * BMv;
  const int colBase = bx * BNv;

  __shared__ __align__(16) bf16_t sA[BMv * 64];
  __shared__ __align__(16) bf16_t sB[BNv * 64];

  A += (size_t)bz * strideA;
  B += (size_t)bz * strideB;

  const int tid  = threadIdx.x;
  const int wave = tid >> 6;
  const int lane = tid & 63;
  const int quad = lane >> 4;
  const int ln16 = lane & 15;

  const int wm = (wave % MW) * 64;
  const int wn = (wave / MW) * WN;

  const int rA = lane >> 3;                       // 0..7 row-in-group
  const int sColOff = ((lane & 7) ^ rA) * 8;      // swizzled chunk offset (elems)
  const bf16_t* pA = A + (size_t)(rowBase + wave * RA + rA) * K + sColOff;
  const bf16_t* pB = B + (size_t)(colBase + wave * RB + rA) * K + sColOff;
  bf16_t* ldsA = sA + wave * RA * 64;
  bf16_t* ldsB = sB + wave * RB * 64;

  f32x4 acc[4][NT] = {};
  f32x4 acc_rs[4] = {};                           // MODE 2: per-row E sums (ones-MFMA)
  bf16x8 ones;
#pragma unroll
  for (int i = 0; i < 8; i++) ones[i] = (bf16_t)1.0f;

  const int Kend = (MODE == 2) ? (K < rowBase + BMv ? K : rowBase + BMv) : K;

  for (int k0 = 0; k0 < Kend; k0 += 64) {
#pragma unroll
    for (int j = 0; j < RA / 8; j++)
      load_lds16(pA + k0 + (size_t)(8 * j) * K, ldsA + j * 512);
#pragma unroll
    for (int j = 0; j < RB / 8; j++)
      load_lds16(pB + k0 + (size_t)(8 * j) * K, ldsB + j * 512);
    __syncthreads();   // drains vmcnt for all waves

#pragma unroll
    for (int kk = 0; kk < 2; kk++) {
      bf16x8 af[4], bfr[NT];
#pragma unroll
      for (int mt = 0; mt < 4; mt++) {
        const int row = wm + mt * 16 + ln16;
        af[mt] = *(const bf16x8*)(sA + row * 64 + (((kk * 4 + quad) ^ (row & 7)) * 8));
      }
#pragma unroll
      for (int nt = 0; nt < NT; nt++) {
        const int row = wn + nt * 16 + ln16;
        bfr[nt] = *(const bf16x8*)(sB + row * 64 + (((kk * 4 + quad) ^ (row & 7)) * 8));
      }
#pragma unroll
      for (int mt = 0; mt < 4; mt++) {
#pragma unroll
        for (int nt = 0; nt < NT; nt++)
          acc[mt][nt] = __builtin_amdgcn_mfma_f32_16x16x32_bf16(af[mt], bfr[nt], acc[mt][nt], 0, 0, 0);
        if constexpr (MODE == 2)
          acc_rs[mt] = __builtin_amdgcn_mfma_f32_16x16x32_bf16(af[mt], ones, acc_rs[mt], 0, 0, 0);
      }
    }
    __syncthreads();
  }

  // epilogue: C/D layout col = lane&15, row = quad*4 + r  [measured m89/m91]
  if constexpr (MODE == 3) {
    const int which = colBase >> 10;               // 128-col tiles never span matrices
    const int cb = colBase & 1023;
    if (which == 2) {
      // V-third: write transposed into Vt[b][e][s]  (b=row>>11, e=col, s=row&2047).
      // Each block covers 128 contiguous s per e-row -> 64B lines fully written
      // within one block/XCD -> L2 write-merge keeps HBM traffic at 33.5 MB.
#pragma unroll
      for (int mt = 0; mt < 4; mt++) {
#pragma unroll
        for (int r = 0; r < 4; r++) {
          const int row = rowBase + wm + mt * 16 + quad * 4 + r;
          const size_t vb = (size_t)(row >> 11) * (1024 * 2048) + (row & 2047);
#pragma unroll
          for (int nt = 0; nt < NT; nt++) {
            const int col = cb + wn + nt * 16 + ln16;
            C2[vb + (size_t)col * 2048] = (OT)acc[mt][nt][r];
          }
        }
      }
    } else {
      OT* Cw = which ? C1 : C0;
#pragma unroll
      for (int mt = 0; mt < 4; mt++) {
#pragma unroll
        for (int r = 0; r < 4; r++) {
          const int row = rowBase + wm + mt * 16 + quad * 4 + r;
#pragma unroll
          for (int nt = 0; nt < NT; nt++) {
            const int col = cb + wn + nt * 16 + ln16;
            Cw[(size_t)row * ldc + col] = (OT)acc[mt][nt][r];
          }
        }
      }
    }
    return;
  }

  OT* Cw = C0 + (size_t)bz * strideC;
#pragma unroll
  for (int mt = 0; mt < 4; mt++) {
#pragma unroll
    for (int r = 0; r < 4; r++) {
      const int row = rowBase + wm + mt * 16 + quad * 4 + r;
      const float rinv = (MODE == 2) ? 1.0f / acc_rs[mt][r] : 1.0f;
#pragma unroll
      for (int nt = 0; nt < NT; nt++) {
        const int col = colBase + wn + nt * 16 + ln16;
        float v = acc[mt][nt][r];
        if constexpr (MODE == 1) {
          v = (col <= row) ? __expf(v * 0.03125f) : 0.0f;   // s/sqrt(1024)
        } else {
          v *= rinv;
        }
        Cw[(size_t)row * ldc + col] = (OT)v;
      }
    }
  }
}

// Fused prep: blocks [0,3072) transpose {Wq,Wk,Wv} fp32 -> bf16 into Wt [3D][D];
// blocks [3072, 7168) convert x fp32 -> bf16 (8 elems/thread, vectorized).
__global__ __launch_bounds__(256)
void prep(const float* __restrict__ w0, const float* __restrict__ w1,
          const float* __restrict__ w2, bf16_t* __restrict__ wt, int D,
          const float* __restrict__ x, bf16_t* __restrict__ xb, long n)
{
  const int b = blockIdx.x;
  const int tid = threadIdx.x;
  __shared__ float tile[32][33];
  if (b < 3072) {
    const int z  = b >> 10;                        // 0..2 selects W matrix
    const int xy = b & 1023;
    const int c0 = (xy & 31) * 32, r0 = (xy >> 5) * 32;
    const int tx = tid & 31, ty = tid >> 5;        // (32, 8)
    const float* in = (z == 0) ? w0 : (z == 1) ? w1 : w2;
    bf16_t* o = wt + (size_t)z * D * D;
#pragma unroll
    for (int i = 0; i < 32; i += 8)
      tile[ty + i][tx] = in[(size_t)(r0 + ty + i) * D + (c0 + tx)];
    __syncthreads();
#pragma unroll
    for (int i = 0; i < 32; i += 8)
      o[(size_t)(c0 + ty + i) * D + (r0 + tx)] = (bf16_t)tile[tx][ty + i];
  } else {
    const long i = ((long)(b - 3072) * 256 + tid) * 8;
    if (i + 7 < n) {
      float4 a = *(const float4*)(x + i);
      float4 c = *(const float4*)(x + i + 4);
      bf16x8 o;
      o[0] = (bf16_t)a.x; o[1] = (bf16_t)a.y; o[2] = (bf16_t)a.z; o[3] = (bf16_t)a.w;
      o[4] = (bf16_t)c.x; o[5] = (bf16_t)c.y; o[6] = (bf16_t)c.z; o[7] = (bf16_t)c.w;
      *(bf16x8*)(xb + i) = o;
    }
  }
}

extern "C" void kernel_launch(void* const* d_in, const int* in_sizes, int n_in,
                              void* d_out, int out_size, void* d_ws, size_t ws_size,
                              hipStream_t stream) {
  const float* x  = (const float*)d_in[0];
  const float* Wq = (const float*)d_in[1];
  const float* Wk = (const float*)d_in[2];
  const float* Wv = (const float*)d_in[3];
  float* out = (float*)d_out;

  const int Bb = 4, S = 2048, D = 1024;
  const int M = Bb * S;  // 8192

  // ws (bf16 elems): Q | K | Vt | Wt(3*D*D) | Xb | (tail)   = 90,177,536 B (fits)
  // Sc (Bb*S*S == 2*M*D) aliases [Xb | tail].
  bf16_t* ws = (bf16_t*)d_ws;
  bf16_t* Q   = ws;
  bf16_t* Kp  = Q  + (size_t)M * D;
  bf16_t* Vt  = Kp + (size_t)M * D;
  bf16_t* Wt  = Vt + (size_t)M * D;          // [3072][1024] stacked
  bf16_t* Xb  = Wt + 3 * (size_t)D * D;
  bf16_t* Sc  = Xb;

  // 1) prep: W transpose+cvt (3072 blocks) || x cvt (4096 blocks)
  prep<<<dim3(3072 + 4096), dim3(256), 0, stream>>>(Wq, Wk, Wv, Wt, D, x, Xb, (long)M * D);

  // 2) fused projections: {Q,K,Vt} = Xb * Wt^T  (4-wave; proven 66-68 us R12-R18)
  gemm_nt_bf16<128, 128, 4, 3, bf16_t><<<dim3(3 * D / 128, M / 128, 1), dim3(256), 0, stream>>>(
      Xb, Wt, Q, Kp, Vt, M, D, D, 0, 0, 0);

  // 3) E = masked-exp(Q*K^T/32)  (8-wave; flat tri grid 544, 68/XCD exact)
  gemm_nt_bf16<128, 128, 8, 1, bf16_t><<<dim3(544, 1, 1), dim3(512), 0, stream>>>(
      Q, Kp, Sc, Sc, Sc, S, D, S, (long)S * D, (long)S * D, (long)S * S);

  // 4) out = (E*V) / (E*ones)  (8-wave; panel-pinned 512 blocks, 68 K-units/XCD)
  gemm_nt_bf16<128, 128, 8, 2, float><<<dim3(512, 1, 1), dim3(512), 0, stream>>>(
      Sc, Vt, out, out, out, S, S, D, (long)S * S, (long)D * S, (long)S * D);
}

// Round 13
// 215.126 us; speedup vs baseline: 1.0978x; 1.0123x over previous
//
#include <hip/hip_runtime.h>
#include <hip/hip_bf16.h>

// CausalAttention: B=4, S=2048, d=1024, single head, causal. fp32 I/O, bf16 MFMA inside.
//
// R21: QKV -> NW=8 (the lever that won R20). R20 counters: QKV 68.2 us, MfmaUtil 31%,
//      Occupancy 24.7% (~8 waves/CU = 2 resident 4-wave blocks) -- same TLP-starved
//      signature PV had at 10% before its NW=8 fix (R19->R20: total -6.6 us, PV/scores
//      left top-5). NW=8 on the same 128^2 tile: per-wave 64x32, acc[4][2], 512 thr,
//      8 waves/block -> 2 waves/SIMD per resident block, ~16 waves/CU at 2 blocks.
//      Template already parameterized (MODE 1/2 run NW=8 in R20); MODE 3 changes only
//      RA (16 rows/wave -> 2 gload_lds) and epilogue NT=2. Zero new sync structure.
//      Banked ladder: R16 delete-work (-14), R20 scores/PV NW=8 (-6.6). Champion 217.8.
//
// Pipeline (4 dispatches):
//   1) prep: Wt[3072][1024] = {Wq,Wk,Wv}^T bf16  ||  Xb = bf16(x)
//   2) {Q,K,Vt} = Xb * Wt^T      (MODE 3, 8-wave 128^2, grid 24x64; V transposed)
//   3) E = masked-exp(Q*K^T/32)  (MODE 1, 8-wave 128^2, flat tri grid 544)
//   4) out = (E*V) / (E*ones)    (MODE 2, 8-wave 128^2, panel-pinned 512)

typedef __bf16 bf16_t;
typedef __bf16 bf16x8 __attribute__((ext_vector_type(8)));
typedef float f32x4 __attribute__((ext_vector_type(4)));

__device__ __forceinline__ void load_lds16(const bf16_t* g, bf16_t* l) {
  __builtin_amdgcn_global_load_lds(
      (__attribute__((address_space(1))) void*)(void*)g,
      (__attribute__((address_space(3))) void*)l,
      16, 0, 0);
}

// C[m][n] = sum_k A[m][k]*B[n][k]  (A:[M][K], B:[N][K] row-major bf16)
// MODE: 1 scores: flat triangular grid, epilogue mask+exp (no rowsum)
//       2 pv: panel-pinned flat grid, K clamped, rowsum via ones-MFMA, epilogue 1/rs
//       3 fused qkv split; V-third written transposed into Vt
// Wave grid: MW x (NW/MW); per-wave tile 64 x WN where WN = BNv*MW/NW.
// LDS swizzle: 16B chunk position p of row r holds global chunk p ^ (r&7);
// fragment reads hit all 32 banks 2-way (free, m136). Conflicts measured 0 (R5-R20).
template <int BMv, int BNv, int NW, int MODE, typename OT>
__global__ __launch_bounds__(NW * 64)
void gemm_nt_bf16(const bf16_t* __restrict__ A, const bf16_t* __restrict__ B,
                  OT* __restrict__ C0, OT* __restrict__ C1, OT* __restrict__ C2,
                  int M, int K, int ldc,
                  long strideA, long strideB, long strideC)
{
  constexpr int MW = BMv / 64;       // wave rows
  constexpr int WN = BNv * MW / NW;  // per-wave N span (64 @ NW=4, 32 @ NW=8)
  constexpr int NT = WN / 16;        // B fragments per wave (4 or 2)
  constexpr int RA = BMv / NW;       // rows staged per wave (A)
  constexpr int RB = BNv / NW;       // rows staged per wave (B)

  int bx, by, bz;
  if constexpr (MODE == 1) {
    // Flat XCD-balanced lower-triangle enumeration (S=2048, 128-tiles, 16 panels/batch).
    // XCD x (= blockIdx.x & 7, m09 round-robin) owns panels {x, 15-x} of every batch:
    // weight (x+1) + (16-x) = 17 tiles per batch -> 68 per XCD, exact balance.
    const int f = blockIdx.x;          // 544 blocks
    const int x = f & 7;
    const int j = f >> 3;              // [0, 68)
    bz = j / 17;
    const int r = j % 17;
    by = (r <= x) ? x : 15 - x;
    bx = (r <= x) ? r : r - (x + 1);
  } else if constexpr (MODE == 2) {
    // PV panel-pinned flat grid: 512 blocks. XCD = f&7 owns 8 E row-panels
    // (4 heavy-first pairs; (16-pr)+(pr+1)=17 -> 68 K-units per XCD exactly).
    // bx fastest: the 8 col-blocks of a panel are consecutive ON ONE XCD -> A-panel
    // fetched once (VERIFIED R19: FETCH 78 -> 23 MB).
    const int f  = blockIdx.x;
    const int xcd = f & 7;
    const int i  = f >> 3;             // [0,64) within XCD
    bx = i & 7;
    const int p  = i >> 3;             // [0,8) panel slot
    const int j  = p & 3;              // pair index
    const int heavy = (p < 4);         // heavy panels first
    const int g  = xcd * 4 + j;        // [0,32) global (bz,pr) pair
    bz = g >> 3;
    const int pr = g & 7;
    by = heavy ? (15 - pr) : pr;
  } else {
    // XCD-aware remap: pin all x-blocks of an A-panel (y,z) to one XCD.
    // Requires (gridDim.y*gridDim.z) % 8 == 0 -- true here (64).
    const int gx = gridDim.x, gy = gridDim.y;
    const int NP = gy * gridDim.z;
    const int P  = NP >> 3;                         // panels per XCD
    const int flat = blockIdx.x + gx * (blockIdx.y + gy * blockIdx.z);
    const int xcd  = flat & 7;
    const int i    = flat >> 3;
    const int pan  = xcd * P + (i % P);
    bx = i / P;
    by = pan % gy;
    bz = pan / gy;
  }

  const int rowBase = by * BMv;
  const int colBase = bx * BNv;

  __shared__ __align__(16) bf16_t sA[BMv * 64];
  __shared__ __align__(16) bf16_t sB[BNv * 64];

  A += (size_t)bz * strideA;
  B += (size_t)bz * strideB;

  const int tid  = threadIdx.x;
  const int wave = tid >> 6;
  const int lane = tid & 63;
  const int quad = lane >> 4;
  const int ln16 = lane & 15;

  const int wm = (wave % MW) * 64;
  const int wn = (wave / MW) * WN;

  const int rA = lane >> 3;                       // 0..7 row-in-group
  const int sColOff = ((lane & 7) ^ rA) * 8;      // swizzled chunk offset (elems)
  const bf16_t* pA = A + (size_t)(rowBase + wave * RA + rA) * K + sColOff;
  const bf16_t* pB = B + (size_t)(colBase + wave * RB + rA) * K + sColOff;
  bf16_t* ldsA = sA + wave * RA * 64;
  bf16_t* ldsB = sB + wave * RB * 64;

  f32x4 acc[4][NT] = {};
  f32x4 acc_rs[4] = {};                           // MODE 2: per-row E sums (ones-MFMA)
  bf16x8 ones;
#pragma unroll
  for (int i = 0; i < 8; i++) ones[i] = (bf16_t)1.0f;

  const int Kend = (MODE == 2) ? (K < rowBase + BMv ? K : rowBase + BMv) : K;

  for (int k0 = 0; k0 < Kend; k0 += 64) {
#pragma unroll
    for (int j = 0; j < RA / 8; j++)
      load_lds16(pA + k0 + (size_t)(8 * j) * K, ldsA + j * 512);
#pragma unroll
    for (int j = 0; j < RB / 8; j++)
      load_lds16(pB + k0 + (size_t)(8 * j) * K, ldsB + j * 512);
    __syncthreads();   // drains vmcnt for all waves

#pragma unroll
    for (int kk = 0; kk < 2; kk++) {
      bf16x8 af[4], bfr[NT];
#pragma unroll
      for (int mt = 0; mt < 4; mt++) {
        const int row = wm + mt * 16 + ln16;
        af[mt] = *(const bf16x8*)(sA + row * 64 + (((kk * 4 + quad) ^ (row & 7)) * 8));
      }
#pragma unroll
      for (int nt = 0; nt < NT; nt++) {
        const int row = wn + nt * 16 + ln16;
        bfr[nt] = *(const bf16x8*)(sB + row * 64 + (((kk * 4 + quad) ^ (row & 7)) * 8));
      }
#pragma unroll
      for (int mt = 0; mt < 4; mt++) {
#pragma unroll
        for (int nt = 0; nt < NT; nt++)
          acc[mt][nt] = __builtin_amdgcn_mfma_f32_16x16x32_bf16(af[mt], bfr[nt], acc[mt][nt], 0, 0, 0);
        if constexpr (MODE == 2)
          acc_rs[mt] = __builtin_amdgcn_mfma_f32_16x16x32_bf16(af[mt], ones, acc_rs[mt], 0, 0, 0);
      }
    }
    __syncthreads();
  }

  // epilogue: C/D layout col = lane&15, row = quad*4 + r  [measured m89/m91]
  if constexpr (MODE == 3) {
    const int which = colBase >> 10;               // 128-col tiles never span matrices
    const int cb = colBase & 1023;
    if (which == 2) {
      // V-third: write transposed into Vt[b][e][s]  (b=row>>11, e=col, s=row&2047).
      // Each block covers 128 contiguous s per e-row -> 64B lines fully written
      // within one block/XCD -> L2 write-merge keeps HBM traffic at 33.5 MB.
#pragma unroll
      for (int mt = 0; mt < 4; mt++) {
#pragma unroll
        for (int r = 0; r < 4; r++) {
          const int row = rowBase + wm + mt * 16 + quad * 4 + r;
          const size_t vb = (size_t)(row >> 11) * (1024 * 2048) + (row & 2047);
#pragma unroll
          for (int nt = 0; nt < NT; nt++) {
            const int col = cb + wn + nt * 16 + ln16;
            C2[vb + (size_t)col * 2048] = (OT)acc[mt][nt][r];
          }
        }
      }
    } else {
      OT* Cw = which ? C1 : C0;
#pragma unroll
      for (int mt = 0; mt < 4; mt++) {
#pragma unroll
        for (int r = 0; r < 4; r++) {
          const int row = rowBase + wm + mt * 16 + quad * 4 + r;
#pragma unroll
          for (int nt = 0; nt < NT; nt++) {
            const int col = cb + wn + nt * 16 + ln16;
            Cw[(size_t)row * ldc + col] = (OT)acc[mt][nt][r];
          }
        }
      }
    }
    return;
  }

  OT* Cw = C0 + (size_t)bz * strideC;
#pragma unroll
  for (int mt = 0; mt < 4; mt++) {
#pragma unroll
    for (int r = 0; r < 4; r++) {
      const int row = rowBase + wm + mt * 16 + quad * 4 + r;
      const float rinv = (MODE == 2) ? 1.0f / acc_rs[mt][r] : 1.0f;
#pragma unroll
      for (int nt = 0; nt < NT; nt++) {
        const int col = colBase + wn + nt * 16 + ln16;
        float v = acc[mt][nt][r];
        if constexpr (MODE == 1) {
          v = (col <= row) ? __expf(v * 0.03125f) : 0.0f;   // s/sqrt(1024)
        } else {
          v *= rinv;
        }
        Cw[(size_t)row * ldc + col] = (OT)v;
      }
    }
  }
}

// Fused prep: blocks [0,3072) transpose {Wq,Wk,Wv} fp32 -> bf16 into Wt [3D][D];
// blocks [3072, 7168) convert x fp32 -> bf16 (8 elems/thread, vectorized).
__global__ __launch_bounds__(256)
void prep(const float* __restrict__ w0, const float* __restrict__ w1,
          const float* __restrict__ w2, bf16_t* __restrict__ wt, int D,
          const float* __restrict__ x, bf16_t* __restrict__ xb, long n)
{
  const int b = blockIdx.x;
  const int tid = threadIdx.x;
  __shared__ float tile[32][33];
  if (b < 3072) {
    const int z  = b >> 10;                        // 0..2 selects W matrix
    const int xy = b & 1023;
    const int c0 = (xy & 31) * 32, r0 = (xy >> 5) * 32;
    const int tx = tid & 31, ty = tid >> 5;        // (32, 8)
    const float* in = (z == 0) ? w0 : (z == 1) ? w1 : w2;
    bf16_t* o = wt + (size_t)z * D * D;
#pragma unroll
    for (int i = 0; i < 32; i += 8)
      tile[ty + i][tx] = in[(size_t)(r0 + ty + i) * D + (c0 + tx)];
    __syncthreads();
#pragma unroll
    for (int i = 0; i < 32; i += 8)
      o[(size_t)(c0 + ty + i) * D + (r0 + tx)] = (bf16_t)tile[tx][ty + i];
  } else {
    const long i = ((long)(b - 3072) * 256 + tid) * 8;
    if (i + 7 < n) {
      float4 a = *(const float4*)(x + i);
      float4 c = *(const float4*)(x + i + 4);
      bf16x8 o;
      o[0] = (bf16_t)a.x; o[1] = (bf16_t)a.y; o[2] = (bf16_t)a.z; o[3] = (bf16_t)a.w;
      o[4] = (bf16_t)c.x; o[5] = (bf16_t)c.y; o[6] = (bf16_t)c.z; o[7] = (bf16_t)c.w;
      *(bf16x8*)(xb + i) = o;
    }
  }
}

extern "C" void kernel_launch(void* const* d_in, const int* in_sizes, int n_in,
                              void* d_out, int out_size, void* d_ws, size_t ws_size,
                              hipStream_t stream) {
  const float* x  = (const float*)d_in[0];
  const float* Wq = (const float*)d_in[1];
  const float* Wk = (const float*)d_in[2];
  const float* Wv = (const float*)d_in[3];
  float* out = (float*)d_out;

  const int Bb = 4, S = 2048, D = 1024;
  const int M = Bb * S;  // 8192

  // ws (bf16 elems): Q | K | Vt | Wt(3*D*D) | Xb | (tail)   = 90,177,536 B (fits)
  // Sc (Bb*S*S == 2*M*D) aliases [Xb | tail].
  bf16_t* ws = (bf16_t*)d_ws;
  bf16_t* Q   = ws;
  bf16_t* Kp  = Q  + (size_t)M * D;
  bf16_t* Vt  = Kp + (size_t)M * D;
  bf16_t* Wt  = Vt + (size_t)M * D;          // [3072][1024] stacked
  bf16_t* Xb  = Wt + 3 * (size_t)D * D;
  bf16_t* Sc  = Xb;

  // 1) prep: W transpose+cvt (3072 blocks) || x cvt (4096 blocks)
  prep<<<dim3(3072 + 4096), dim3(256), 0, stream>>>(Wq, Wk, Wv, Wt, D, x, Xb, (long)M * D);

  // 2) fused projections: {Q,K,Vt} = Xb * Wt^T  (8-wave; R20 occupancy lever applied)
  gemm_nt_bf16<128, 128, 8, 3, bf16_t><<<dim3(3 * D / 128, M / 128, 1), dim3(512), 0, stream>>>(
      Xb, Wt, Q, Kp, Vt, M, D, D, 0, 0, 0);

  // 3) E = masked-exp(Q*K^T/32)  (8-wave; flat tri grid 544, 68/XCD exact)
  gemm_nt_bf16<128, 128, 8, 1, bf16_t><<<dim3(544, 1, 1), dim3(512), 0, stream>>>(
      Q, Kp, Sc, Sc, Sc, S, D, S, (long)S * D, (long)S * D, (long)S * S);

  // 4) out = (E*V) / (E*ones)  (8-wave; panel-pinned 512 blocks, 68 K-units/XCD)
  gemm_nt_bf16<128, 128, 8, 2, float><<<dim3(512, 1, 1), dim3(512), 0, stream>>>(
      Sc, Vt, out, out, out, S, S, D, (long)S * S, (long)D * S, (long)S * D);
}